// Round 1
// baseline (37728.143 us; speedup 1.0000x reference)
//
#include <hip/hip_runtime.h>
#include <math.h>

// Problem constants (match reference)
#define NB 1024      // batch
#define NH 512       // hidden
#define NT 256       // time steps
#define NCD 2        // per-step output dims

// LSTM GEMM tile
#define BM 64
#define BN 32
#define BK 32

__device__ __forceinline__ float sigf(float x) { return 1.0f / (1.0f + expf(-x)); }

// ---------------------------------------------------------------------------
// init: [h0 | c0] = concat(zp,zs,zst) @ W_proj^T + b_proj ; h0->h1,h2 c0->c1,c2
// grid: NB/4 blocks, 256 threads
// ---------------------------------------------------------------------------
__global__ __launch_bounds__(256) void init_kernel(
    const float* __restrict__ zp, const float* __restrict__ zs,
    const float* __restrict__ zst, const float* __restrict__ Wp,
    const float* __restrict__ bp,
    float* __restrict__ h1, float* __restrict__ c1,
    float* __restrict__ h2, float* __restrict__ c2)
{
    __shared__ float z[4][256];
    const int tid = threadIdx.x;
    const int b0  = blockIdx.x * 4;
    for (int i = tid; i < 4 * 256; i += 256) {
        const int bb = i >> 8, k = i & 255;
        float v;
        if (k < 64)       v = zp [(b0 + bb) * 64  + k];
        else if (k < 128) v = zs [(b0 + bb) * 64  + (k - 64)];
        else              v = zst[(b0 + bb) * 128 + (k - 128)];
        z[bb][k] = v;
    }
    __syncthreads();
    for (int rt = 0; rt < 4; ++rt) {
        const int r = rt * 256 + tid;          // 0..1023 output row
        const float bias = bp[r];
        float a0 = bias, a1 = bias, a2 = bias, a3 = bias;
        for (int k = 0; k < 256; ++k) {
            const float w = Wp[r * 256 + k];
            a0 += z[0][k] * w; a1 += z[1][k] * w;
            a2 += z[2][k] * w; a3 += z[3][k] * w;
        }
        const float acc[4] = {a0, a1, a2, a3};
        for (int bb = 0; bb < 4; ++bb) {
            const int b = b0 + bb;
            if (r < NH) { h1[b * NH + r] = acc[bb]; h2[b * NH + r] = acc[bb]; }
            else        { c1[b * NH + r - NH] = acc[bb]; c2[b * NH + r - NH] = acc[bb]; }
        }
    }
}

// ---------------------------------------------------------------------------
// One-time transpose of Wo1 (256x512) -> Wo1T (512x256) for coalesced reads
// ---------------------------------------------------------------------------
__global__ __launch_bounds__(256) void transpose_wo1(
    const float* __restrict__ Wo1, float* __restrict__ Wo1T)
{
    const int idx = blockIdx.x * 256 + threadIdx.x;  // < 256*512
    const int r = idx >> 9, k = idx & 511;
    Wo1T[k * 256 + r] = Wo1[idx];
}

// ---------------------------------------------------------------------------
// Fused LSTM cell: gates = xin@Wih^T + hprev@Whh^T + (bih+bhh); update c,
// write hnext.  Tile: BM=64 batch x BN=32 units, all 4 gates per thread-output.
// Each thread: 8 batch rows x 1 unit x 4 gates = 32 fp32 accumulators.
// grid: (NH/BN, NB/BM) = (16,16), 256 threads.
// hprev/hnext must be distinct buffers (ping-pong). c updated in place
// (each element read+written by exactly its owning thread).
// ---------------------------------------------------------------------------
__global__ __launch_bounds__(256) void lstm_kernel(
    const float* __restrict__ hprev,   // NB x NH
    const float* __restrict__ xin,     // NB x Kx
    const int Kx,
    const float* __restrict__ Whh,     // 4NH x NH
    const float* __restrict__ Wih,     // 4NH x Kx
    const float* __restrict__ bih, const float* __restrict__ bhh,
    float* __restrict__ c, float* __restrict__ hnext)
{
    __shared__ float hs[BK][BM + 4];       // k-major activations (b128 reads)
    __shared__ float ws[4 * BN][BK + 1];   // row = g*BN + u, stride 33 (conflict-free)
    const int tid = threadIdx.x;
    const int u   = tid & (BN - 1);        // unit within tile
    const int bg  = tid >> 5;              // 0..7 -> owns batch rows bg*8 .. bg*8+7
    const int u0  = blockIdx.x * BN;
    const int b0  = blockIdx.y * BM;

    float acc[4][8];
#pragma unroll
    for (int g = 0; g < 4; ++g)
#pragma unroll
        for (int j = 0; j < 8; ++j) acc[g][j] = 0.0f;

    for (int pass = 0; pass < 2; ++pass) {
        const float* __restrict__ A = pass ? xin : hprev;
        const float* __restrict__ W = pass ? Wih : Whh;
        const int K = pass ? Kx : NH;
        if (K >= BK) {
            for (int k0 = 0; k0 < K; k0 += BK) {
                __syncthreads();   // protect LDS from previous tile's readers
                // stage A tile (BM x BK) transposed into hs[k][b]
#pragma unroll
                for (int i = 0; i < 2; ++i) {
                    const int idx = tid * 2 + i;        // 0..511 float4 slots
                    const int row = idx >> 3;           // 0..63 batch row
                    const int kq  = (idx & 7) * 4;      // 0..28
                    const float4 v = *(const float4*)&A[(size_t)(b0 + row) * K + k0 + kq];
                    hs[kq + 0][row] = v.x; hs[kq + 1][row] = v.y;
                    hs[kq + 2][row] = v.z; hs[kq + 3][row] = v.w;
                }
                // stage W tile: 4 gates x BN units x BK k
#pragma unroll
                for (int i = 0; i < 4; ++i) {
                    const int idx = tid * 4 + i;        // 0..1023 float4 slots
                    const int row = idx >> 3;           // 0..127 (= g*32 + uu)
                    const int kq  = (idx & 7) * 4;
                    const int g = row >> 5, uu = row & 31;
                    const float4 v = *(const float4*)&W[(size_t)(g * NH + u0 + uu) * K + k0 + kq];
                    ws[row][kq + 0] = v.x; ws[row][kq + 1] = v.y;
                    ws[row][kq + 2] = v.z; ws[row][kq + 3] = v.w;
                }
                __syncthreads();
#pragma unroll
                for (int k = 0; k < BK; ++k) {
                    const float4 hA = *(const float4*)&hs[k][bg * 8 + 0];
                    const float4 hB = *(const float4*)&hs[k][bg * 8 + 4];
                    const float w0 = ws[0 * BN + u][k];
                    const float w1 = ws[1 * BN + u][k];
                    const float w2 = ws[2 * BN + u][k];
                    const float w3 = ws[3 * BN + u][k];
                    const float hv[8] = {hA.x, hA.y, hA.z, hA.w, hB.x, hB.y, hB.z, hB.w};
#pragma unroll
                    for (int j = 0; j < 8; ++j) {
                        acc[0][j] += hv[j] * w0;
                        acc[1][j] += hv[j] * w1;
                        acc[2][j] += hv[j] * w2;
                        acc[3][j] += hv[j] * w3;
                    }
                }
            }
        } else {
            // tiny-K path (LSTM1 input x, K=2) — straight from global (L2-hot)
            for (int kk = 0; kk < K; ++kk) {
                float wv[4];
#pragma unroll
                for (int g = 0; g < 4; ++g) wv[g] = W[(size_t)(g * NH + u0 + u) * K + kk];
#pragma unroll
                for (int j = 0; j < 8; ++j) {
                    const float xv = A[(size_t)(b0 + bg * 8 + j) * K + kk];
#pragma unroll
                    for (int g = 0; g < 4; ++g) acc[g][j] += xv * wv[g];
                }
            }
        }
    }

    // cell update epilogue
    const int ug = u0 + u;
    const float bb0 = bih[0 * NH + ug] + bhh[0 * NH + ug];
    const float bb1 = bih[1 * NH + ug] + bhh[1 * NH + ug];
    const float bb2 = bih[2 * NH + ug] + bhh[2 * NH + ug];
    const float bb3 = bih[3 * NH + ug] + bhh[3 * NH + ug];
#pragma unroll
    for (int j = 0; j < 8; ++j) {
        const int b = b0 + bg * 8 + j;
        const float iv = sigf (acc[0][j] + bb0);
        const float fv = sigf (acc[1][j] + bb1);
        const float gv = tanhf(acc[2][j] + bb2);
        const float ov = sigf (acc[3][j] + bb3);
        const int idx = b * NH + ug;
        const float cn = fv * c[idx] + iv * gv;
        c[idx] = cn;
        hnext[idx] = ov * tanhf(cn);
    }
}

// ---------------------------------------------------------------------------
// out-MLP: y = relu(h2@Wo1^T + bo1)@Wo2^T + bo2 ; writes d_out[b][t][:] and
// the x feedback buffer. One block per 4 batch rows; thread = hidden neuron r.
// ---------------------------------------------------------------------------
__global__ __launch_bounds__(256) void out_kernel(
    const float* __restrict__ h2, const float* __restrict__ Wo1T,
    const float* __restrict__ bo1, const float* __restrict__ Wo2,
    const float* __restrict__ bo2, float* __restrict__ xbuf,
    float* __restrict__ out, const int t)
{
    __shared__ float hsh[4][NH];
    __shared__ float red[8][4];
    const int tid = threadIdx.x;
    const int b0  = blockIdx.x * 4;
    for (int i = tid; i < 4 * NH; i += 256) hsh[i >> 9][i & 511] = h2[(size_t)b0 * NH + i];
    __syncthreads();
    const float base = bo1[tid];
    float a0 = base, a1 = base, a2 = base, a3 = base;
    for (int k = 0; k < NH; ++k) {
        const float w = Wo1T[k * 256 + tid];       // coalesced
        a0 += hsh[0][k] * w; a1 += hsh[1][k] * w;
        a2 += hsh[2][k] * w; a3 += hsh[3][k] * w;
    }
    const float w20 = Wo2[tid], w21 = Wo2[256 + tid];
    float p[8];
    {
        const float h0 = fmaxf(a0, 0.f), h1 = fmaxf(a1, 0.f);
        const float h2_ = fmaxf(a2, 0.f), h3 = fmaxf(a3, 0.f);
        p[0] = h0 * w20; p[1] = h0 * w21;
        p[2] = h1 * w20; p[3] = h1 * w21;
        p[4] = h2_ * w20; p[5] = h2_ * w21;
        p[6] = h3 * w20; p[7] = h3 * w21;
    }
#pragma unroll
    for (int off = 32; off > 0; off >>= 1)
#pragma unroll
        for (int q = 0; q < 8; ++q) p[q] += __shfl_down(p[q], off, 64);
    const int wave = tid >> 6, lane = tid & 63;
    if (lane == 0)
#pragma unroll
        for (int q = 0; q < 8; ++q) red[q][wave] = p[q];
    __syncthreads();
    if (tid < 8) {
        const int bb = tid >> 1, cc = tid & 1;
        const float v = red[tid][0] + red[tid][1] + red[tid][2] + red[tid][3] + bo2[cc];
        const int b = b0 + bb;
        xbuf[b * NCD + cc] = v;
        out[(size_t)b * (NT * NCD) + t * NCD + cc] = v;
    }
}

// ---------------------------------------------------------------------------
extern "C" void kernel_launch(void* const* d_in, const int* in_sizes, int n_in,
                              void* d_out, int out_size, void* d_ws, size_t ws_size,
                              hipStream_t stream)
{
    const float* zp   = (const float*)d_in[0];
    const float* zsk  = (const float*)d_in[1];
    const float* zst  = (const float*)d_in[2];
    const float* Wp   = (const float*)d_in[3];
    const float* bp   = (const float*)d_in[4];
    const float* Wih1 = (const float*)d_in[5];
    const float* Whh1 = (const float*)d_in[6];
    const float* bih1 = (const float*)d_in[7];
    const float* bhh1 = (const float*)d_in[8];
    const float* Wih2 = (const float*)d_in[9];
    const float* Whh2 = (const float*)d_in[10];
    const float* bih2 = (const float*)d_in[11];
    const float* bhh2 = (const float*)d_in[12];
    const float* Wo1  = (const float*)d_in[13];
    const float* bo1  = (const float*)d_in[14];
    const float* Wo2  = (const float*)d_in[15];
    const float* bo2  = (const float*)d_in[16];

    float* w = (float*)d_ws;
    const size_t BH = (size_t)NB * NH;      // 524288 floats
    float* h1a = w;
    float* h1b = h1a + BH;
    float* c1  = h1b + BH;
    float* h2a = c1  + BH;
    float* h2b = h2a + BH;
    float* c2  = h2b + BH;
    float* xb   = c2 + BH;                  // NB*NCD, padded region of 4096
    float* Wo1T = xb + 4096;                // 512*256
    // total ws use: (6*524288 + 4096 + 131072)*4 B ~= 13.2 MB

    hipMemsetAsync(xb, 0, NB * NCD * sizeof(float), stream);   // x0 = 0
    init_kernel<<<NB / 4, 256, 0, stream>>>(zp, zsk, zst, Wp, bp, h1a, c1, h2a, c2);
    transpose_wo1<<<(256 * 512) / 256, 256, 0, stream>>>(Wo1, Wo1T);

    float* h1c = h1a; float* h1n = h1b;
    float* h2c = h2a; float* h2n = h2b;
    float* outp = (float*)d_out;
    const dim3 lgrid(NH / BN, NB / BM);     // (16,16)
    for (int t = 0; t < NT; ++t) {
        lstm_kernel<<<lgrid, 256, 0, stream>>>(h1c, xb,  NCD, Whh1, Wih1, bih1, bhh1, c1, h1n);
        lstm_kernel<<<lgrid, 256, 0, stream>>>(h2c, h1n, NH,  Whh2, Wih2, bih2, bhh2, c2, h2n);
        out_kernel<<<NB / 4, 256, 0, stream>>>(h2n, Wo1T, bo1, Wo2, bo2, xb, outp, t);
        float* tmp = h1c; h1c = h1n; h1n = tmp;
        tmp = h2c; h2c = h2n; h2n = tmp;
    }
}

// Round 2
// 14375.554 us; speedup vs baseline: 2.6245x; 2.6245x over previous
//
#include <hip/hip_runtime.h>
#include <math.h>

// Problem constants
#define NB 1024      // batch
#define NH 512       // hidden
#define NT 256       // time steps
#define NCD 2        // per-step output dims

typedef unsigned short u16;
typedef __bf16 bf16x8 __attribute__((ext_vector_type(8)));
typedef float  f32x4  __attribute__((ext_vector_type(4)));

__device__ __forceinline__ float sigf(float x) { return 1.0f / (1.0f + expf(-x)); }
__device__ __forceinline__ float b2f(u16 u) {
    union { unsigned i; float f; } v; v.i = ((unsigned)u) << 16; return v.f;
}
__device__ __forceinline__ u16 f2b(float f) {   // RTNE
    union { float f; unsigned i; } v; v.f = f;
    unsigned r = v.i + 0x7fffu + ((v.i >> 16) & 1u);
    return (u16)(r >> 16);
}

// ---------------------------------------------------------------------------
// weight conversion fp32 -> bf16 for the three K=512 GEMM weights (1M each)
// ---------------------------------------------------------------------------
__global__ __launch_bounds__(256) void convert3(
    const float* __restrict__ a, const float* __restrict__ b,
    const float* __restrict__ c,
    u16* __restrict__ oa, u16* __restrict__ ob, u16* __restrict__ oc)
{
    const int i = blockIdx.x * 256 + threadIdx.x;   // < 2048*512
    oa[i] = f2b(a[i]); ob[i] = f2b(b[i]); oc[i] = f2b(c[i]);
}

__global__ __launch_bounds__(256) void bsum_k(
    const float* __restrict__ bi1, const float* __restrict__ bh1,
    const float* __restrict__ bi2, const float* __restrict__ bh2,
    float* __restrict__ o1, float* __restrict__ o2)
{
    const int i = blockIdx.x * 256 + threadIdx.x;   // < 2048
    o1[i] = bi1[i] + bh1[i];
    o2[i] = bi2[i] + bh2[i];
}

// ---------------------------------------------------------------------------
// init: [h0 | c0] = z @ W_proj^T + b_proj ; h0 (bf16) -> h1,h2 ; c0 (f32)
// ---------------------------------------------------------------------------
__global__ __launch_bounds__(256) void init_kernel(
    const float* __restrict__ zp, const float* __restrict__ zs,
    const float* __restrict__ zst, const float* __restrict__ Wp,
    const float* __restrict__ bp,
    u16* __restrict__ h1, float* __restrict__ c1,
    u16* __restrict__ h2, float* __restrict__ c2)
{
    __shared__ float z[4][256];
    const int tid = threadIdx.x;
    const int b0  = blockIdx.x * 4;
    for (int i = tid; i < 4 * 256; i += 256) {
        const int bb = i >> 8, k = i & 255;
        float v;
        if (k < 64)       v = zp [(b0 + bb) * 64  + k];
        else if (k < 128) v = zs [(b0 + bb) * 64  + (k - 64)];
        else              v = zst[(b0 + bb) * 128 + (k - 128)];
        z[bb][k] = v;
    }
    __syncthreads();
    for (int rt = 0; rt < 4; ++rt) {
        const int r = rt * 256 + tid;          // 0..1023
        const float bias = bp[r];
        float a0 = bias, a1 = bias, a2 = bias, a3 = bias;
        for (int k = 0; k < 256; ++k) {
            const float w = Wp[r * 256 + k];
            a0 += z[0][k] * w; a1 += z[1][k] * w;
            a2 += z[2][k] * w; a3 += z[3][k] * w;
        }
        const float acc[4] = {a0, a1, a2, a3};
        for (int bb = 0; bb < 4; ++bb) {
            const int b = b0 + bb;
            if (r < NH) {
                h1[b * NH + r] = f2b(acc[bb]);
                h2[b * NH + r] = f2b(acc[bb]);
            } else {
                c1[b * NH + r - NH] = acc[bb];
                c2[b * NH + r - NH] = acc[bb];
            }
        }
    }
}

// ---------------------------------------------------------------------------
// One-time transpose of Wo1 (256x512) -> Wo1T (512x256), fp32
// ---------------------------------------------------------------------------
__global__ __launch_bounds__(256) void transpose_wo1(
    const float* __restrict__ Wo1, float* __restrict__ Wo1T)
{
    const int idx = blockIdx.x * 256 + threadIdx.x;  // < 256*512
    const int r = idx >> 9, k = idx & 511;
    Wo1T[k * 256 + r] = Wo1[idx];
}

// ---------------------------------------------------------------------------
// MFMA fused LSTM cell.
// gates[b][g*NH+u] = sum_p A_p @ W_p^T  (+ x-term for layer 1) + bsum
// Tile: 64 batch x 32 units x 4 gates; grid (NH/32, NB/64) = (16,16).
// 256 threads = 4 waves; wave w computes gate w via mfma_f32_16x16x32_bf16.
// LDS: XOR-swizzled 16B chunks (conflict-free b128); gates exchanged through
// LDS for the fused pointwise cell update (all 4 gates needed per (b,u)).
// ---------------------------------------------------------------------------
__global__ __launch_bounds__(256) void lstm_mfma(
    const u16* __restrict__ A0, const u16* __restrict__ W0,
    const u16* __restrict__ A1, const u16* __restrict__ W1,
    const float* __restrict__ bsum,
    const float* __restrict__ xin, const float* __restrict__ Wx,  // layer1 else null
    float* __restrict__ c, u16* __restrict__ hnext,
    const int npass)
{
    // staging: As[64][64] u16 (8KB) + Ws[128][64] u16 (16KB)  -> 24576 B
    // epilogue: eg[4][64][34] f32 -> 34816 B   (aliased union)
    __shared__ __align__(16) char smem[34816];
    u16*   As = (u16*)smem;             // row stride 64, chunk-swizzled
    u16*   Ws = (u16*)smem + 64 * 64;   // row = g*32+uu, stride 64, swizzled
    float* eg = (float*)smem;           // [g][b][u] stride 34

    const int tid  = threadIdx.x;
    const int lane = tid & 63;
    const int wv   = tid >> 6;          // wave id == gate id
    const int l15  = lane & 15;
    const int q    = lane >> 4;         // 0..3
    const int u0   = blockIdx.x * 32;
    const int b0   = blockIdx.y * 64;

    f32x4 acc[4][2];
#pragma unroll
    for (int mi = 0; mi < 4; ++mi)
#pragma unroll
        for (int ni = 0; ni < 2; ++ni)
            acc[mi][ni] = (f32x4){0.f, 0.f, 0.f, 0.f};

    for (int p = 0; p < npass; ++p) {
        const u16* __restrict__ A = p ? A1 : A0;
        const u16* __restrict__ W = p ? W1 : W0;
        for (int k0 = 0; k0 < NH; k0 += 64) {
            __syncthreads();
            // stage A tile: 64 rows x 64 k = 512 chunks of 8 bf16, 2/thread
#pragma unroll
            for (int i = 0; i < 2; ++i) {
                const int cid = tid * 2 + i;
                const int row = cid >> 3;
                const int kc  = cid & 7;              // k-chunk
                const float4 v = *(const float4*)(A + (size_t)(b0 + row) * NH + k0 + kc * 8);
                const int cs = kc ^ (row & 7);        // xor swizzle
                *(float4*)(As + row * 64 + cs * 8) = v;
            }
            // stage W tile: 4 gates x 32 units x 64 k = 1024 chunks, 4/thread
#pragma unroll
            for (int i = 0; i < 4; ++i) {
                const int cid  = tid * 4 + i;
                const int wrow = cid >> 3;            // 0..127 = g*32+uu
                const int kc   = cid & 7;
                const int g = wrow >> 5, uu = wrow & 31;
                const float4 v = *(const float4*)(W + (size_t)(g * NH + u0 + uu) * NH + k0 + kc * 8);
                const int cs = kc ^ (wrow & 7);
                *(float4*)(Ws + wrow * 64 + cs * 8) = v;
            }
            __syncthreads();
            // compute: 2 k-halves of 32; per half: 2 B-frags + 4 A-frags -> 8 MFMAs
#pragma unroll
            for (int kh = 0; kh < 2; ++kh) {
                bf16x8 bfr[2];
#pragma unroll
                for (int ni = 0; ni < 2; ++ni) {
                    const int row = wv * 32 + ni * 16 + l15;
                    const int cs  = (kh * 4 + q) ^ (row & 7);
                    bfr[ni] = *(const bf16x8*)(Ws + row * 64 + cs * 8);
                }
#pragma unroll
                for (int mi = 0; mi < 4; ++mi) {
                    const int row = mi * 16 + l15;
                    const int cs  = (kh * 4 + q) ^ (row & 7);
                    const bf16x8 av = *(const bf16x8*)(As + row * 64 + cs * 8);
                    acc[mi][0] = __builtin_amdgcn_mfma_f32_16x16x32_bf16(av, bfr[0], acc[mi][0], 0, 0, 0);
                    acc[mi][1] = __builtin_amdgcn_mfma_f32_16x16x32_bf16(av, bfr[1], acc[mi][1], 0, 0, 0);
                }
            }
        }
    }

    __syncthreads();
    // dump pre-activations to LDS: eg[gate][b_local][u_local]
    // D layout: row = q*4 + r (batch), col = l15 (unit)   [m89-verified]
#pragma unroll
    for (int mi = 0; mi < 4; ++mi)
#pragma unroll
        for (int ni = 0; ni < 2; ++ni)
#pragma unroll
            for (int r = 0; r < 4; ++r)
                eg[(wv * 64 + mi * 16 + q * 4 + r) * 34 + ni * 16 + l15] = acc[mi][ni][r];
    __syncthreads();

    // fused pointwise cell update: thread -> unit u, 8 batch rows
    const int u  = tid & 31;
    const int bq = tid >> 5;            // 0..7
    const int ug = u0 + u;
    float bs[4], wx0[4], wx1[4];
#pragma unroll
    for (int g = 0; g < 4; ++g) bs[g] = bsum[g * NH + ug];
    if (Wx) {
#pragma unroll
        for (int g = 0; g < 4; ++g) {
            wx0[g] = Wx[(g * NH + ug) * 2 + 0];
            wx1[g] = Wx[(g * NH + ug) * 2 + 1];
        }
    }
#pragma unroll
    for (int jj = 0; jj < 8; ++jj) {
        const int bl = bq * 8 + jj;
        const int b  = b0 + bl;
        float gv[4];
#pragma unroll
        for (int g = 0; g < 4; ++g) gv[g] = eg[(g * 64 + bl) * 34 + u] + bs[g];
        if (Wx) {
            const float x0 = xin[b * 2], x1 = xin[b * 2 + 1];
#pragma unroll
            for (int g = 0; g < 4; ++g) gv[g] += x0 * wx0[g] + x1 * wx1[g];
        }
        const float iv = sigf(gv[0]);
        const float fv = sigf(gv[1]);
        const float gg = tanhf(gv[2]);
        const float ov = sigf(gv[3]);
        const size_t idx = (size_t)b * NH + ug;
        const float cn = fv * c[idx] + iv * gg;
        c[idx] = cn;
        hnext[idx] = f2b(ov * tanhf(cn));
    }
}

// ---------------------------------------------------------------------------
// out-MLP: y = relu(h2@Wo1^T + bo1)@Wo2^T + bo2 ; h2 is bf16 now.
// ---------------------------------------------------------------------------
__global__ __launch_bounds__(256) void out_kernel(
    const u16* __restrict__ h2, const float* __restrict__ Wo1T,
    const float* __restrict__ bo1, const float* __restrict__ Wo2,
    const float* __restrict__ bo2, float* __restrict__ xbuf,
    float* __restrict__ out, const int t)
{
    __shared__ float hsh[4][NH];
    __shared__ float red[8][4];
    const int tid = threadIdx.x;
    const int b0  = blockIdx.x * 4;
    for (int i = tid; i < 4 * NH; i += 256)
        hsh[i >> 9][i & 511] = b2f(h2[(size_t)b0 * NH + i]);
    __syncthreads();
    const float base = bo1[tid];
    float a0 = base, a1 = base, a2 = base, a3 = base;
    for (int k = 0; k < NH; ++k) {
        const float w = Wo1T[k * 256 + tid];
        a0 += hsh[0][k] * w; a1 += hsh[1][k] * w;
        a2 += hsh[2][k] * w; a3 += hsh[3][k] * w;
    }
    const float w20 = Wo2[tid], w21 = Wo2[256 + tid];
    float p[8];
    {
        const float h0 = fmaxf(a0, 0.f), h1 = fmaxf(a1, 0.f);
        const float h2_ = fmaxf(a2, 0.f), h3 = fmaxf(a3, 0.f);
        p[0] = h0 * w20; p[1] = h0 * w21;
        p[2] = h1 * w20; p[3] = h1 * w21;
        p[4] = h2_ * w20; p[5] = h2_ * w21;
        p[6] = h3 * w20; p[7] = h3 * w21;
    }
#pragma unroll
    for (int off = 32; off > 0; off >>= 1)
#pragma unroll
        for (int qq = 0; qq < 8; ++qq) p[qq] += __shfl_down(p[qq], off, 64);
    const int wave = tid >> 6, lane = tid & 63;
    if (lane == 0)
#pragma unroll
        for (int qq = 0; qq < 8; ++qq) red[qq][wave] = p[qq];
    __syncthreads();
    if (tid < 8) {
        const int bb = tid >> 1, cc = tid & 1;
        const float v = red[tid][0] + red[tid][1] + red[tid][2] + red[tid][3] + bo2[cc];
        const int b = b0 + bb;
        xbuf[b * NCD + cc] = v;
        out[(size_t)b * (NT * NCD) + t * NCD + cc] = v;
    }
}

// ---------------------------------------------------------------------------
extern "C" void kernel_launch(void* const* d_in, const int* in_sizes, int n_in,
                              void* d_out, int out_size, void* d_ws, size_t ws_size,
                              hipStream_t stream)
{
    const float* zp   = (const float*)d_in[0];
    const float* zsk  = (const float*)d_in[1];
    const float* zst  = (const float*)d_in[2];
    const float* Wp   = (const float*)d_in[3];
    const float* bp   = (const float*)d_in[4];
    const float* Wih1 = (const float*)d_in[5];
    const float* Whh1 = (const float*)d_in[6];
    const float* bih1 = (const float*)d_in[7];
    const float* bhh1 = (const float*)d_in[8];
    const float* Wih2 = (const float*)d_in[9];
    const float* Whh2 = (const float*)d_in[10];
    const float* bih2 = (const float*)d_in[11];
    const float* bhh2 = (const float*)d_in[12];
    const float* Wo1  = (const float*)d_in[13];
    const float* bo1  = (const float*)d_in[14];
    const float* Wo2  = (const float*)d_in[15];
    const float* bo2  = (const float*)d_in[16];

    const size_t BH = (size_t)NB * NH;          // 524288
    u16*   h1a   = (u16*)d_ws;
    u16*   h1b   = h1a + BH;
    u16*   h2a   = h1b + BH;
    u16*   h2b   = h2a + BH;
    float* c1    = (float*)(h2b + BH);
    float* c2    = c1 + BH;
    float* xb    = c2 + BH;                     // 2048 used (pad 4096)
    float* Wo1T  = xb + 4096;                   // 131072
    float* bs1   = Wo1T + 131072;               // 2048
    float* bs2   = bs1 + 2048;                  // 2048
    u16*   Whh1b = (u16*)(bs2 + 2048);          // 1048576 each
    u16*   Wih2b = Whh1b + 1048576;
    u16*   Whh2b = Wih2b + 1048576;
    // total ~14.6 MB of d_ws

    convert3<<<(2048 * 512) / 256, 256, 0, stream>>>(Whh1, Wih2, Whh2, Whh1b, Wih2b, Whh2b);
    bsum_k<<<2048 / 256, 256, 0, stream>>>(bih1, bhh1, bih2, bhh2, bs1, bs2);
    transpose_wo1<<<(256 * 512) / 256, 256, 0, stream>>>(Wo1, Wo1T);
    hipMemsetAsync(xb, 0, NB * NCD * sizeof(float), stream);   // x0 = 0
    init_kernel<<<NB / 4, 256, 0, stream>>>(zp, zsk, zst, Wp, bp, h1a, c1, h2a, c2);

    u16* h1c = h1a; u16* h1n = h1b;
    u16* h2c = h2a; u16* h2n = h2b;
    float* outp = (float*)d_out;
    const dim3 lgrid(NH / 32, NB / 64);         // (16,16)
    for (int t = 0; t < NT; ++t) {
        lstm_mfma<<<lgrid, 256, 0, stream>>>(h1c, Whh1b, (const u16*)0, (const u16*)0,
                                             bs1, xb, Wih1, c1, h1n, 1);
        lstm_mfma<<<lgrid, 256, 0, stream>>>(h1n, Wih2b, h2c, Whh2b,
                                             bs2, (const float*)0, (const float*)0, c2, h2n, 2);
        out_kernel<<<NB / 4, 256, 0, stream>>>(h2n, Wo1T, bo1, Wo2, bo2, xb, outp, t);
        u16* tmp = h1c; h1c = h1n; h1n = tmp;
        tmp = h2c; h2c = h2n; h2n = tmp;
    }
}

// Round 4
// 11926.822 us; speedup vs baseline: 3.1633x; 1.2053x over previous
//
#include <hip/hip_runtime.h>
#include <math.h>

// Problem constants
#define NB 1024      // batch
#define NH 512       // hidden
#define NT 256       // time steps
#define NCD 2        // per-step output dims

typedef unsigned short u16;
typedef __bf16 bf16x8 __attribute__((ext_vector_type(8)));
typedef float  f32x4  __attribute__((ext_vector_type(4)));

#define MFMA_BF16 __builtin_amdgcn_mfma_f32_16x16x32_bf16

__device__ __forceinline__ float sigf(float x) { return 1.0f / (1.0f + expf(-x)); }
__device__ __forceinline__ float b2f(u16 u) {
    union { unsigned i; float f; } v; v.i = ((unsigned)u) << 16; return v.f;
}
__device__ __forceinline__ u16 f2b(float f) {   // RTNE
    union { float f; unsigned i; } v; v.f = f;
    unsigned r = v.i + 0x7fffu + ((v.i >> 16) & 1u);
    return (u16)(r >> 16);
}

// async 16B global -> LDS (direct-to-shared DMA). LDS dest must be
// wave-uniform base; HW scatters lane L to base + L*16.
__device__ __forceinline__ void async_cp16(const void* gptr, void* lptr) {
    __builtin_amdgcn_global_load_lds(
        (const __attribute__((address_space(1))) unsigned int*)gptr,
        (__attribute__((address_space(3))) unsigned int*)lptr,
        16, 0, 0);
}

// ---------------------------------------------------------------------------
// weight conversion fp32 -> bf16 (three 2048x512 LSTM weights)
// ---------------------------------------------------------------------------
__global__ __launch_bounds__(256) void convert3(
    const float* __restrict__ a, const float* __restrict__ b,
    const float* __restrict__ c,
    u16* __restrict__ oa, u16* __restrict__ ob, u16* __restrict__ oc)
{
    const int i = blockIdx.x * 256 + threadIdx.x;   // < 2048*512
    oa[i] = f2b(a[i]); ob[i] = f2b(b[i]); oc[i] = f2b(c[i]);
}

__global__ __launch_bounds__(256) void bsum_k(
    const float* __restrict__ bi1, const float* __restrict__ bh1,
    const float* __restrict__ bi2, const float* __restrict__ bh2,
    float* __restrict__ o1, float* __restrict__ o2)
{
    const int i = blockIdx.x * 256 + threadIdx.x;   // < 2048
    o1[i] = bi1[i] + bh1[i];
    o2[i] = bi2[i] + bh2[i];
}

// ---------------------------------------------------------------------------
// One-time transpose of Wo1 (256x512) -> Wo1T (512x256), fp32  [R2-verified]
// ---------------------------------------------------------------------------
__global__ __launch_bounds__(256) void transpose_wo1(
    const float* __restrict__ Wo1, float* __restrict__ Wo1T)
{
    const int idx = blockIdx.x * 256 + threadIdx.x;  // < 256*512
    const int r = idx >> 9, k = idx & 511;
    Wo1T[k * 256 + r] = Wo1[idx];
}

// ---------------------------------------------------------------------------
// init: [h0 | c0] = z @ W_proj^T + b_proj ; h0 (bf16) -> h1,h2 ; c0 (f32)
// ---------------------------------------------------------------------------
__global__ __launch_bounds__(256) void init_kernel(
    const float* __restrict__ zp, const float* __restrict__ zs,
    const float* __restrict__ zst, const float* __restrict__ Wp,
    const float* __restrict__ bp,
    u16* __restrict__ h1, float* __restrict__ c1,
    u16* __restrict__ h2, float* __restrict__ c2)
{
    __shared__ float z[4][256];
    const int tid = threadIdx.x;
    const int b0  = blockIdx.x * 4;
    for (int i = tid; i < 4 * 256; i += 256) {
        const int bb = i >> 8, k = i & 255;
        float v;
        if (k < 64)       v = zp [(b0 + bb) * 64  + k];
        else if (k < 128) v = zs [(b0 + bb) * 64  + (k - 64)];
        else              v = zst[(b0 + bb) * 128 + (k - 128)];
        z[bb][k] = v;
    }
    __syncthreads();
    for (int rt = 0; rt < 4; ++rt) {
        const int r = rt * 256 + tid;          // 0..1023
        const float bias = bp[r];
        float a0 = bias, a1 = bias, a2 = bias, a3 = bias;
        for (int k = 0; k < 256; ++k) {
            const float w = Wp[r * 256 + k];
            a0 += z[0][k] * w; a1 += z[1][k] * w;
            a2 += z[2][k] * w; a3 += z[3][k] * w;
        }
        const float acc[4] = {a0, a1, a2, a3};
        for (int bb = 0; bb < 4; ++bb) {
            const int b = b0 + bb;
            if (r < NH) {
                h1[b * NH + r] = f2b(acc[bb]);
                h2[b * NH + r] = f2b(acc[bb]);
            } else {
                c1[b * NH + r - NH] = acc[bb];
                c2[b * NH + r - NH] = acc[bb];
            }
        }
    }
}

// ---------------------------------------------------------------------------
// MFMA fused LSTM cell, v3 (under test this round).
// Tile: 64 batch x 32 units x 4 gates; grid (16,16); 512 threads = 8 waves.
// Wave w: gate g = w&3, batch-half mh = w>>2.
// K-loop: macro-tiles of 64, double-buffered (2 x 24KB LDS), staged via
// global_load_lds w=16; XOR swizzle applied on the global-side chunk choice.
// ---------------------------------------------------------------------------
__global__ __launch_bounds__(512) void lstm_mfma(
    const u16* __restrict__ A0, const u16* __restrict__ W0,
    const u16* __restrict__ A1, const u16* __restrict__ W1,
    const float* __restrict__ bsum,
    const float* __restrict__ xin, const float* __restrict__ Wx,  // layer1 else null
    float* __restrict__ c, u16* __restrict__ hnext,
    const int npass)
{
    // 2 buffers x (As 64x64 bf16 = 8KB + Ws 128x64 bf16 = 16KB) = 49152 B
    // epilogue eg[4][64][33] f32 = 33792 B aliases buffer space
    __shared__ __align__(16) char smem[49152];
    float* eg = (float*)smem;

    const int tid  = threadIdx.x;
    const int lane = tid & 63;
    const int wv   = tid >> 6;          // 0..7
    const int g    = wv & 3;            // gate
    const int mh   = wv >> 2;           // batch half
    const int l15  = lane & 15;
    const int q    = lane >> 4;         // 0..3
    const int u0   = blockIdx.x * 32;
    const int b0   = blockIdx.y * 64;

    // 1536 chunks/macro: [0,512) As (row=c>>3), [512,1536) Ws (wrow=(c-512)>>3)
    int goff[3], isa[3];
#pragma unroll
    for (int i = 0; i < 3; ++i) {
        const int cidx = (wv * 3 + i) * 64 + lane;   // 0..1535
        if (cidx < 512) {
            const int row = cidx >> 3;
            const int kc  = (cidx & 7) ^ (row & 7);
            goff[i] = (b0 + row) * NH + kc * 8;
            isa[i]  = 1;
        } else {
            const int rc   = cidx - 512;
            const int wrow = rc >> 3;                // g*32+uu
            const int kc   = (rc & 7) ^ (wrow & 7);
            goff[i] = ((wrow >> 5) * NH + u0 + (wrow & 31)) * NH + kc * 8;
            isa[i]  = 0;
        }
    }

    f32x4 acc[2][2];
#pragma unroll
    for (int mi = 0; mi < 2; ++mi)
#pragma unroll
        for (int ni = 0; ni < 2; ++ni)
            acc[mi][ni] = (f32x4){0.f, 0.f, 0.f, 0.f};

    const int M = npass * 8;            // total macro-tiles

    auto issue = [&](int m) {
        const u16* __restrict__ Ap = (m < 8) ? A0 : A1;
        const u16* __restrict__ Wp = (m < 8) ? W0 : W1;
        const int k0 = (m & 7) * 64;
        char* base = smem + (m & 1) * 24576;
#pragma unroll
        for (int i = 0; i < 3; ++i) {
            const u16* gp = (isa[i] ? Ap : Wp) + (goff[i] + k0);
            async_cp16((const void*)gp, (void*)(base + ((wv * 3 + i) << 10)));
        }
    };

    issue(0);
    for (int m = 0; m < M; ++m) {
        __syncthreads();                 // drains vmcnt: loads(m) complete
        if (m + 1 < M) issue(m + 1);     // prefetch into other buffer
        const char* bA = smem + (m & 1) * 24576;
        const char* bW = bA + 8192;
#pragma unroll
        for (int khi = 0; khi < 2; ++khi) {
            bf16x8 bfr[2];
#pragma unroll
            for (int ni = 0; ni < 2; ++ni) {
                const int wrow = g * 32 + ni * 16 + l15;
                const int j = (khi * 4 + q) ^ (wrow & 7);
                bfr[ni] = *(const bf16x8*)(bW + wrow * 128 + j * 16);
            }
#pragma unroll
            for (int mi = 0; mi < 2; ++mi) {
                const int row = mh * 32 + mi * 16 + l15;
                const int j = (khi * 4 + q) ^ (row & 7);
                const bf16x8 av = *(const bf16x8*)(bA + row * 128 + j * 16);
                acc[mi][0] = MFMA_BF16(av, bfr[0], acc[mi][0], 0, 0, 0);
                acc[mi][1] = MFMA_BF16(av, bfr[1], acc[mi][1], 0, 0, 0);
            }
        }
    }

    __syncthreads();
    // dump gate pre-activations: eg[g][b_local][u_local], stride 33
    // C/D layout: row(batch) = q*4+r, col(unit) = l15   [m89-verified]
#pragma unroll
    for (int mi = 0; mi < 2; ++mi)
#pragma unroll
        for (int ni = 0; ni < 2; ++ni)
#pragma unroll
            for (int r = 0; r < 4; ++r)
                eg[(g * 64 + mh * 32 + mi * 16 + q * 4 + r) * 33 + ni * 16 + l15]
                    = acc[mi][ni][r];
    __syncthreads();

    // fused pointwise cell update: thread -> unit u, 4 batch rows
    const int u  = tid & 31;
    const int bg = tid >> 5;            // 0..15
    const int ug = u0 + u;
    float bs[4], wx0[4], wx1[4];
#pragma unroll
    for (int g4 = 0; g4 < 4; ++g4) bs[g4] = bsum[g4 * NH + ug];
    if (Wx) {
#pragma unroll
        for (int g4 = 0; g4 < 4; ++g4) {
            wx0[g4] = Wx[(g4 * NH + ug) * 2 + 0];
            wx1[g4] = Wx[(g4 * NH + ug) * 2 + 1];
        }
    }
#pragma unroll
    for (int jj = 0; jj < 4; ++jj) {
        const int bl = bg * 4 + jj;
        const int b  = b0 + bl;
        float gv[4];
#pragma unroll
        for (int g4 = 0; g4 < 4; ++g4) gv[g4] = eg[(g4 * 64 + bl) * 33 + u] + bs[g4];
        if (Wx) {
            const float x0 = xin[b * 2], x1 = xin[b * 2 + 1];
#pragma unroll
            for (int g4 = 0; g4 < 4; ++g4) gv[g4] += x0 * wx0[g4] + x1 * wx1[g4];
        }
        const float iv = sigf(gv[0]);
        const float fv = sigf(gv[1]);
        const float gg = tanhf(gv[2]);
        const float ov = sigf(gv[3]);
        const size_t idx = (size_t)b * NH + ug;
        const float cn = fv * c[idx] + iv * gg;
        c[idx] = cn;
        hnext[idx] = f2b(ov * tanhf(cn));
    }
}

// ---------------------------------------------------------------------------
// out-MLP (R2-verified fp32 path): y = relu(h2@Wo1^T+bo1)@Wo2^T+bo2
// ---------------------------------------------------------------------------
__global__ __launch_bounds__(256) void out_kernel(
    const u16* __restrict__ h2, const float* __restrict__ Wo1T,
    const float* __restrict__ bo1, const float* __restrict__ Wo2,
    const float* __restrict__ bo2, float* __restrict__ xbuf,
    float* __restrict__ out, const int t)
{
    __shared__ float hsh[4][NH];
    __shared__ float red[8][4];
    const int tid = threadIdx.x;
    const int b0  = blockIdx.x * 4;
    for (int i = tid; i < 4 * NH; i += 256)
        hsh[i >> 9][i & 511] = b2f(h2[(size_t)b0 * NH + i]);
    __syncthreads();
    const float base = bo1[tid];
    float a0 = base, a1 = base, a2 = base, a3 = base;
    for (int k = 0; k < NH; ++k) {
        const float w = Wo1T[k * 256 + tid];
        a0 += hsh[0][k] * w; a1 += hsh[1][k] * w;
        a2 += hsh[2][k] * w; a3 += hsh[3][k] * w;
    }
    const float w20 = Wo2[tid], w21 = Wo2[256 + tid];
    float p[8];
    {
        const float h0 = fmaxf(a0, 0.f), h1 = fmaxf(a1, 0.f);
        const float h2_ = fmaxf(a2, 0.f), h3 = fmaxf(a3, 0.f);
        p[0] = h0 * w20; p[1] = h0 * w21;
        p[2] = h1 * w20; p[3] = h1 * w21;
        p[4] = h2_ * w20; p[5] = h2_ * w21;
        p[6] = h3 * w20; p[7] = h3 * w21;
    }
#pragma unroll
    for (int off = 32; off > 0; off >>= 1)
#pragma unroll
        for (int qq = 0; qq < 8; ++qq) p[qq] += __shfl_down(p[qq], off, 64);
    const int wave = tid >> 6, lane = tid & 63;
    if (lane == 0)
#pragma unroll
        for (int qq = 0; qq < 8; ++qq) red[qq][wave] = p[qq];
    __syncthreads();
    if (tid < 8) {
        const int bb = tid >> 1, cc = tid & 1;
        const float v = red[tid][0] + red[tid][1] + red[tid][2] + red[tid][3] + bo2[cc];
        const int b = b0 + bb;
        xbuf[b * NCD + cc] = v;
        out[(size_t)b * (NT * NCD) + t * NCD + cc] = v;
    }
}

// ---------------------------------------------------------------------------
extern "C" void kernel_launch(void* const* d_in, const int* in_sizes, int n_in,
                              void* d_out, int out_size, void* d_ws, size_t ws_size,
                              hipStream_t stream)
{
    const float* zp   = (const float*)d_in[0];
    const float* zsk  = (const float*)d_in[1];
    const float* zst  = (const float*)d_in[2];
    const float* Wp   = (const float*)d_in[3];
    const float* bp   = (const float*)d_in[4];
    const float* Wih1 = (const float*)d_in[5];
    const float* Whh1 = (const float*)d_in[6];
    const float* bih1 = (const float*)d_in[7];
    const float* bhh1 = (const float*)d_in[8];
    const float* Wih2 = (const float*)d_in[9];
    const float* Whh2 = (const float*)d_in[10];
    const float* bih2 = (const float*)d_in[11];
    const float* bhh2 = (const float*)d_in[12];
    const float* Wo1  = (const float*)d_in[13];
    const float* bo1  = (const float*)d_in[14];
    const float* Wo2  = (const float*)d_in[15];
    const float* bo2  = (const float*)d_in[16];

    const size_t BH = (size_t)NB * NH;          // 524288
    u16*   h1a   = (u16*)d_ws;
    u16*   h1b   = h1a + BH;
    u16*   h2a   = h1b + BH;
    u16*   h2b   = h2a + BH;
    float* c1    = (float*)(h2b + BH);
    float* c2    = c1 + BH;
    float* xb    = c2 + BH;                     // 2048 used (pad 4096)
    float* bs1   = xb + 4096;                   // 2048
    float* bs2   = bs1 + 2048;                  // 2048
    float* Wo1T  = bs2 + 2048;                  // 131072 floats
    u16*   Whh1b = (u16*)(Wo1T + 131072);       // 1048576 each
    u16*   Wih2b = Whh1b + 1048576;
    u16*   Whh2b = Wih2b + 1048576;
    // total ~14.6 MB of d_ws

    convert3<<<(2048 * 512) / 256, 256, 0, stream>>>(Whh1, Wih2, Whh2, Whh1b, Wih2b, Whh2b);
    transpose_wo1<<<(256 * 512) / 256, 256, 0, stream>>>(Wo1, Wo1T);
    bsum_k<<<2048 / 256, 256, 0, stream>>>(bih1, bhh1, bih2, bhh2, bs1, bs2);
    hipMemsetAsync(xb, 0, NB * NCD * sizeof(float), stream);   // x0 = 0
    init_kernel<<<NB / 4, 256, 0, stream>>>(zp, zsk, zst, Wp, bp, h1a, c1, h2a, c2);

    u16* h1c = h1a; u16* h1n = h1b;
    u16* h2c = h2a; u16* h2n = h2b;
    float* outp = (float*)d_out;
    const dim3 lgrid(NH / 32, NB / 64);         // (16,16)
    for (int t = 0; t < NT; ++t) {
        lstm_mfma<<<lgrid, 512, 0, stream>>>(h1c, Whh1b, (const u16*)0, (const u16*)0,
                                             bs1, xb, Wih1, c1, h1n, 1);
        lstm_mfma<<<lgrid, 512, 0, stream>>>(h1n, Wih2b, h2c, Whh2b,
                                             bs2, (const float*)0, (const float*)0, c2, h2n, 2);
        out_kernel<<<NB / 4, 256, 0, stream>>>(h2n, Wo1T, bo1, Wo2, bo2, xb, outp, t);
        u16* tmp = h1c; h1c = h1n; h1n = tmp;
        tmp = h2c; h2c = h2n; h2n = tmp;
    }
}